// Round 4
// baseline (315.057 us; speedup 1.0000x reference)
//
#include <hip/hip_runtime.h>
#include <stdint.h>

typedef unsigned short u16;
typedef __attribute__((ext_vector_type(8))) short short8;   // 8 bf16 = 4 VGPRs
typedef __attribute__((ext_vector_type(4))) float f32x4;

#define LOG2E 1.44269504088896340736f
#define CS (0.03125f * LOG2E)   // softmax scale 1/sqrt(E)=1/32, folded into exp2 domain
// Problem dims
#define BB 4
#define NN 2048
#define EE 1024
#define HH 16
#define DD 64
#define MM 8192   // B*N
#define C3 3072   // 3*E

#if __has_builtin(__builtin_amdgcn_exp2f)
#define EXP2(x) __builtin_amdgcn_exp2f(x)
#else
#define EXP2(x) exp2f(x)
#endif

__device__ __forceinline__ u16 f2bf(float f) {
  union { float f; unsigned u; } v; v.f = f;
  unsigned r = v.u + 0x7fffu + ((v.u >> 16) & 1u);
  return (u16)(r >> 16);
}

#if __has_builtin(__builtin_amdgcn_cvt_pk_bf16_f32)
typedef __attribute__((ext_vector_type(2))) __bf16 bf16x2;
__device__ __forceinline__ unsigned pk2(float a, float b) {
  union { bf16x2 v; unsigned u; } c;
  c.v = __builtin_amdgcn_cvt_pk_bf16_f32(a, b);
  return c.u;
}
#else
__device__ __forceinline__ unsigned pk2(float a, float b) {
  union { float f; unsigned u; } x, y; x.f = a; y.f = b;
  return ((x.u + 0x8000u) >> 16) | ((y.u + 0x8000u) & 0xffff0000u);
}
#endif

__device__ __forceinline__ void async16(const void* g, void* l) {
  __builtin_amdgcn_global_load_lds((const __attribute__((address_space(1))) void*)g,
                                   (__attribute__((address_space(3))) void*)l,
                                   16, 0, 0);
}

// in-tile V key permutation (matches in-register P fragment assembly):
// stored slot s from true key t (6 bits): s = (t5, t3, t2, t4, t1, t0)
__device__ __forceinline__ int vperm(int t) {
  return (t & 0x23) | ((t & 8) << 1) | ((t & 4) << 1) | ((t & 16) >> 2);
}

// ---------------- fused prep kernel ----------------
__global__ __launch_bounds__(256) void prep_kernel(const float* __restrict__ x, u16* __restrict__ xb,
                                                   const float* __restrict__ Wqkv, u16* __restrict__ WqkvT,
                                                   const float* __restrict__ Wproj, u16* __restrict__ WprojT) {
  __shared__ float tile[32][33];
  const int bid = blockIdx.x;
  if (bid < 8192) {
    int i = (bid * 256 + threadIdx.x) * 4;
    float4 v = *(const float4*)(x + i);
    ushort4 o; o.x = f2bf(v.x); o.y = f2bf(v.y); o.z = f2bf(v.z); o.w = f2bf(v.w);
    *(ushort4*)(xb + i) = o;
    return;
  }
  const int permute = bid < 11264 ? 1 : 0;
  const float* W = permute ? Wqkv : Wproj;
  u16* Wt = permute ? WqkvT : WprojT;
  const int ncols = permute ? C3 : EE;
  const int t = permute ? bid - 8192 : bid - 11264;
  const int nbx = permute ? 96 : 32;
  const int c0 = (t % nbx) * 32, k0 = (t / nbx) * 32;
  const int tx = threadIdx.x & 31, ty = threadIdx.x >> 5;  // ty 0..7
#pragma unroll
  for (int r = 0; r < 32; r += 8)
    tile[ty + r][tx] = W[(size_t)(k0 + ty + r) * ncols + c0 + tx];
  __syncthreads();
#pragma unroll
  for (int r = 0; r < 32; r += 8) {
    int c = c0 + ty + r;
    int cp = c;
    if (permute) {
      int tt = c % 3, hh = c / 192, d = (c / 3) % 64;
      cp = tt * 1024 + hh * 64 + d;
    }
    Wt[(size_t)cp * EE + k0 + tx] = f2bf(tile[tx][ty + r]);
  }
}

// ---------------- GEMM core v3: 256x256, 8 waves, 4-phase/K-tile counted-vmcnt ----------------
// m201-template port (same phase granularity: 8 phases per 2 K-tiles).
// Per-wave output 128x64 (8mi x 4ci frags): 24 ds_read_b128 feed 64 MFMAs per
// K-tile (R=2.67) -- the LDS-read-BW lever that capped R1 at 26% MfmaUtil.
// LDS in CHUNK ORDER (global source pre-scattered, LDS dest linear, read =
// const + lane*16B): zero bank conflicts without st_16x32 swizzle.
// Each phase: {ds_read quadrant frags || stage 1/4 of tile t+1 -> builtin
// s_barrier -> 16 MFMA in setprio(1) -> counted vmcnt -> builtin s_barrier}.
// vmcnt never drains to 0 in steady state. FIFO trace (2 loads per stage call):
//   entering tile t: outstanding = [B1(t),A1(t)] = 4
//   ph(0,0): +A0(t+1) -> 6; end vmcnt(4) drains B1(t)   [read next phase]
//   ph(0,1): +B0(t+1) -> 6; end vmcnt(4) drains A1(t)   [read next phase]
//   ph(1,0): +B1(t+1) -> 6; end barrier only (ph(1,1) reads nothing)
//   ph(1,1): +A1(t+1) -> 8; end vmcnt(4) drains A0,B0(t+1) -> invariant holds
// Cross-wave safety: every wave runs the same stage schedule, so "own-loads
// drained (counted vmcnt) + barrier" ==> all waves' loads for the next-phase
// reads have landed. Tail (pf=false): vmcnt(2) then vmcnt(0).
template <int KDIM>
__device__ __forceinline__ void gemm_core8(const u16* __restrict__ A, const u16* __restrict__ Bt,
                                           int m0, int n0, u16* As, u16* Bs, f32x4 (*acc)[4]) {
  constexpr int NT = KDIM / 64;
  const int tid = threadIdx.x, lane = tid & 63, wave = tid >> 6;
  const int wm = wave >> 2, wn = wave & 3;

#pragma unroll
  for (int i = 0; i < 8; i++)
#pragma unroll
    for (int j = 0; j < 4; j++) acc[i][j] = (f32x4){0.f, 0.f, 0.f, 0.f};

  // stage half of the A-tile (mi-half h) of K-tile t into buffer t&1
  auto stageA = [&](int t, int h) {
    const u16* Ab = A + (size_t)m0 * KDIM + t * 64;
    u16* dst = As + (t & 1) * 16384;
#pragma unroll
    for (int i = 0; i < 2; i++) {
      int j = i * 512 + tid;
      int lj = j & 63, mi_l = (j >> 6) & 3, wmj = (j >> 8) & 1, ksj = (j >> 9) & 1;
      int mi = h * 4 + mi_l;
      int c = ((ksj * 2 + wmj) * 8 + mi) * 64 + lj;
      int row = wmj * 128 + mi * 16 + (lj & 15);
      int k = ksj * 32 + (lj >> 4) * 8;
      async16(Ab + (size_t)row * KDIM + k, dst + c * 8);
    }
  };
  // stage half of the B-tile (ci pair cset) of K-tile t into buffer t&1
  auto stageB = [&](int t, int cset) {
    const u16* Bb = Bt + (size_t)n0 * KDIM + t * 64;
    u16* dst = Bs + (t & 1) * 16384;
#pragma unroll
    for (int i = 0; i < 2; i++) {
      int j = i * 512 + tid;
      int lj = j & 63, ci_l = (j >> 6) & 1, wnj = (j >> 7) & 3, ksj = (j >> 9) & 1;
      int ci = cset * 2 + ci_l;
      int c = ((ksj * 4 + wnj) * 4 + ci) * 64 + lj;
      int row = wnj * 64 + ci * 16 + (lj & 15);
      int k = ksj * 32 + (lj >> 4) * 8;
      async16(Bb + (size_t)row * KDIM + k, dst + c * 8);
    }
  };

  // prologue: full tile 0 in order A0,B0,B1,A1; drain A0,B0; keep B1,A1 in flight
  stageA(0, 0); stageB(0, 0); stageB(0, 1); stageA(0, 1);
  asm volatile("s_waitcnt vmcnt(4)" ::: "memory");
  __builtin_amdgcn_s_barrier();

  short8 af[4][2], bf[4][2];
#pragma unroll 2
  for (int t = 0; t < NT; ++t) {
    const int buf = t & 1;
    const u16* Ab = As + buf * 16384;
    const u16* Bb = Bs + buf * 16384;
    const bool pf = (t + 1 < NT);

    // ---- phase (0,0): read A0 + B0, stage A0(t+1), MFMA quadrant (mi 0-3, ci 0-1)
#pragma unroll
    for (int m = 0; m < 4; m++)
#pragma unroll
      for (int ks = 0; ks < 2; ks++)
        af[m][ks] = *(const short8*)&Ab[(((ks * 2 + wm) * 8 + m) * 64 + lane) * 8];
#pragma unroll
    for (int c = 0; c < 2; c++)
#pragma unroll
      for (int ks = 0; ks < 2; ks++)
        bf[c][ks] = *(const short8*)&Bb[(((ks * 4 + wn) * 4 + c) * 64 + lane) * 8];
    if (pf) stageA(t + 1, 0);
    __builtin_amdgcn_s_barrier();
    __builtin_amdgcn_s_setprio(1);
#pragma unroll
    for (int m = 0; m < 4; m++)
#pragma unroll
      for (int c = 0; c < 2; c++)
#pragma unroll
        for (int ks = 0; ks < 2; ks++)
          acc[m][c] = __builtin_amdgcn_mfma_f32_16x16x32_bf16(af[m][ks], bf[c][ks], acc[m][c], 0, 0, 0);
    __builtin_amdgcn_s_setprio(0);
    if (pf) asm volatile("s_waitcnt vmcnt(4)" ::: "memory");
    else    asm volatile("s_waitcnt vmcnt(2)" ::: "memory");
    __builtin_amdgcn_s_barrier();

    // ---- phase (0,1): read B1, stage B0(t+1), MFMA quadrant (mi 0-3, ci 2-3)
#pragma unroll
    for (int c = 2; c < 4; c++)
#pragma unroll
      for (int ks = 0; ks < 2; ks++)
        bf[c][ks] = *(const short8*)&Bb[(((ks * 4 + wn) * 4 + c) * 64 + lane) * 8];
    if (pf) stageB(t + 1, 0);
    __builtin_amdgcn_s_barrier();
    __builtin_amdgcn_s_setprio(1);
#pragma unroll
    for (int m = 0; m < 4; m++)
#pragma unroll
      for (int c = 2; c < 4; c++)
#pragma unroll
        for (int ks = 0; ks < 2; ks++)
          acc[m][c] = __builtin_amdgcn_mfma_f32_16x16x32_bf16(af[m][ks], bf[c][ks], acc[m][c], 0, 0, 0);
    __builtin_amdgcn_s_setprio(0);
    if (pf) asm volatile("s_waitcnt vmcnt(4)" ::: "memory");
    else    asm volatile("s_waitcnt vmcnt(0)" ::: "memory");
    __builtin_amdgcn_s_barrier();

    // ---- phase (1,0): read A1 (overwrite af), stage B1(t+1), MFMA (mi 4-7, ci 0-1)
#pragma unroll
    for (int m = 0; m < 4; m++)
#pragma unroll
      for (int ks = 0; ks < 2; ks++)
        af[m][ks] = *(const short8*)&Ab[(((ks * 2 + wm) * 8 + 4 + m) * 64 + lane) * 8];
    if (pf) stageB(t + 1, 1);
    __builtin_amdgcn_s_barrier();
    __builtin_amdgcn_s_setprio(1);
#pragma unroll
    for (int m = 0; m < 4; m++)
#pragma unroll
      for (int c = 0; c < 2; c++)
#pragma unroll
        for (int ks = 0; ks < 2; ks++)
          acc[4 + m][c] = __builtin_amdgcn_mfma_f32_16x16x32_bf16(af[m][ks], bf[c][ks], acc[4 + m][c], 0, 0, 0);
    __builtin_amdgcn_s_setprio(0);
    __builtin_amdgcn_s_barrier();   // no vmcnt: phase (1,1) reads nothing new

    // ---- phase (1,1): stage A1(t+1), MFMA (mi 4-7, ci 2-3)
    if (pf) stageA(t + 1, 1);
    __builtin_amdgcn_s_barrier();
    __builtin_amdgcn_s_setprio(1);
#pragma unroll
    for (int m = 0; m < 4; m++)
#pragma unroll
      for (int c = 2; c < 4; c++)
#pragma unroll
        for (int ks = 0; ks < 2; ks++)
          acc[4 + m][c] = __builtin_amdgcn_mfma_f32_16x16x32_bf16(af[m][ks], bf[c][ks], acc[4 + m][c], 0, 0, 0);
    __builtin_amdgcn_s_setprio(0);
    if (pf) {
      asm volatile("s_waitcnt vmcnt(4)" ::: "memory");  // drain A0,B0 of t+1; keep B1,A1
      __builtin_amdgcn_s_barrier();
    }
  }
}

// ---------------- merged K/V chunk layout ----------------
// KVt[bh][tile(32)][8192 u16]:
//   first 4096  = K-tile chunks: idx = ks*2048 + mi*512 + (q*16+r16)*8 + e
//   second 4096 = V-tile chunks: idx = kp*2048 + ci*512 + (q*16+r16)*8 + e
//                 (V key-slots permuted by vperm)

// QKV GEMM: X[8192,1024] @ WqkvT -> Q(pre-scaled by CS) to [bh][n][d], K/V to KVt chunks
__global__ __launch_bounds__(512, 1) void gemm_qkv(const u16* __restrict__ Xb, const u16* __restrict__ Wt,
                                                   const float* __restrict__ bqkv, u16* __restrict__ Qb,
                                                   u16* __restrict__ KVt) {
  __shared__ __align__(16) u16 As[2 * 16384];  // 64KB
  __shared__ __align__(16) u16 Bs[2 * 16384];  // 64KB
  f32x4 acc[8][4];
  const int m0 = blockIdx.y * 256, n0 = blockIdx.x * 256;
  gemm_core8<EE>(Xb, Wt, m0, n0, As, Bs, acc);
  const int tid = threadIdx.x, lane = tid & 63, wave = tid >> 6;
  const int q = lane >> 4, r16 = lane & 15;
  const int wm = wave >> 2, wn = wave & 3;
  const int t = n0 >> 10;                    // whole block in one t-region (256 | 1024)
  const int b = m0 >> 11;                    // whole block in one batch (256 | 2048)
#pragma unroll
  for (int ci = 0; ci < 4; ci++) {
    const int cp = n0 + wn * 64 + ci * 16 + r16;  // permuted col: t*1024 + h*64 + d
    const int hh = (cp >> 6) & 15, d = cp & 63;
    const float bias = bqkv[hh * 192 + d * 3 + t];  // bias permute folded in
    if (t == 0) {
#pragma unroll
      for (int mi = 0; mi < 8; mi++)
#pragma unroll
        for (int r = 0; r < 4; r++) {
          const int m = m0 + wm * 128 + mi * 16 + q * 4 + r;
          Qb[((size_t)(b * 16 + hh) * 2048 + (m & 2047)) * 64 + d] = f2bf((acc[mi][ci][r] + bias) * CS);
        }
    } else if (t == 1) {
      const size_t bhbase = (size_t)(b * 16 + hh) * 32;
      const size_t dpart = (size_t)(d >> 5) * 2048 + ((d >> 3) & 3) * 128 + (d & 7);
#pragma unroll
      for (int mi = 0; mi < 8; mi++)
#pragma unroll
        for (int r = 0; r < 4; r++) {
          const int key = (m0 + wm * 128 + mi * 16 + q * 4 + r) & 2047;
          KVt[(bhbase + (key >> 6)) * 8192 + dpart + ((key >> 4) & 3) * 512 + (key & 15) * 8] =
              f2bf(acc[mi][ci][r] + bias);
        }
    } else {
      const size_t bhbase = (size_t)(b * 16 + hh) * 32;
      const int dpart = (d >> 4) * 512 + (d & 15) * 8;
#pragma unroll
      for (int mi = 0; mi < 8; mi++) {
        const int nb = (m0 + wm * 128 + mi * 16 + q * 4) & 2047;
        const int sb = vperm(nb & 63);  // 4-aligned -> 4-contiguous preserved
        ushort4 w;
        w.x = f2bf(acc[mi][ci][0] + bias);
        w.y = f2bf(acc[mi][ci][1] + bias);
        w.z = f2bf(acc[mi][ci][2] + bias);
        w.w = f2bf(acc[mi][ci][3] + bias);
        *(ushort4*)&KVt[(bhbase + (nb >> 6)) * 8192 + 4096 + (sb >> 5) * 2048 +
                        ((sb >> 3) & 3) * 128 + dpart + (sb & 7)] = w;
      }
    }
  }
}

// Proj GEMM: O[8192,1024] @ WprojT + bproj -> fp32 out (same 256x256 8-phase core)
__global__ __launch_bounds__(512, 1) void gemm_proj(const u16* __restrict__ Ob, const u16* __restrict__ Wt,
                                                    const float* __restrict__ bp, float* __restrict__ out) {
  __shared__ __align__(16) u16 As[2 * 16384];
  __shared__ __align__(16) u16 Bs[2 * 16384];
  f32x4 acc[8][4];
  const int m0 = blockIdx.y * 256, n0 = blockIdx.x * 256;
  gemm_core8<EE>(Ob, Wt, m0, n0, As, Bs, acc);
  const int tid = threadIdx.x, lane = tid & 63, wave = tid >> 6;
  const int q = lane >> 4, r16 = lane & 15;
  const int wm = wave >> 2, wn = wave & 3;
#pragma unroll
  for (int ci = 0; ci < 4; ci++) {
    const int col = n0 + wn * 64 + ci * 16 + r16;
    const float bias = bp[col];
#pragma unroll
    for (int mi = 0; mi < 8; mi++)
#pragma unroll
      for (int r = 0; r < 4; r++) {
        const int m = m0 + wm * 128 + mi * 16 + q * 4 + r;
        out[(size_t)m * EE + col] = acc[mi][ci][r] + bias;
      }
  }
}

// ---------------- flash attention (unchanged: chunk-order LDS, conflicts = 0) ----------------
__global__ __launch_bounds__(256, 4) void attn_kernel(const u16* __restrict__ Qg, const u16* __restrict__ KVg,
                                                      u16* __restrict__ Ob) {
  __shared__ __align__(16) u16 KVd[2][8192];  // [buf][K:4096 | V:4096] chunk-ordered
  const int tid = threadIdx.x, lane = tid & 63, wave = tid >> 6;
  const int q = lane >> 4, r16 = lane & 15;
  const int id = blockIdx.x + 16 * blockIdx.y;
  const int g = id & 7, s = id >> 3;
  const int bh = g * 8 + (s >> 4);
  const int q0 = (s & 15) * 128;
  const u16* Qp = Qg + ((size_t)bh * NN + q0) * DD;
  const u16* KVp = KVg + (size_t)bh * (32 * 8192);

  short8 qf[2][2];  // [nj][ks]
#pragma unroll
  for (int nj = 0; nj < 2; nj++)
#pragma unroll
    for (int ks = 0; ks < 2; ks++)
      qf[nj][ks] = *(const short8*)(Qp + (wave * 32 + nj * 16 + r16) * 64 + ks * 32 + q * 8);

#pragma unroll
  for (int i = 0; i < 4; i++) {
    int c = i * 256 + tid;
    async16(KVp + c * 8, &KVd[0][c * 8]);
  }
  __syncthreads();  // tile0 landed

  f32x4 o[2][4];
  f32x4 ol[2];
#pragma unroll
  for (int i = 0; i < 2; i++) {
    ol[i] = (f32x4){0.f, 0.f, 0.f, 0.f};
#pragma unroll
    for (int j = 0; j < 4; j++) o[i][j] = (f32x4){0.f, 0.f, 0.f, 0.f};
  }
  const short8 ones = {16256, 16256, 16256, 16256, 16256, 16256, 16256, 16256};  // bf16 1.0

  for (int j = 0; j < 32; j++) {
    const int buf = j & 1;
    if (j < 31) {
      const u16* src = KVp + (size_t)(j + 1) * 8192;
#pragma unroll
      for (int i = 0; i < 4; i++) {
        int c = i * 256 + tid;
        async16(src + c * 8, &KVd[buf ^ 1][c * 8]);
      }
    }

    f32x4 st[4][2];
#pragma unroll
    for (int mi = 0; mi < 4; mi++)
#pragma unroll
      for (int nj = 0; nj < 2; nj++) st[mi][nj] = (f32x4){0.f, 0.f, 0.f, 0.f};
#pragma unroll
    for (int ks = 0; ks < 2; ks++) {
      short8 kf[4];
#pragma unroll
      for (int mi = 0; mi < 4; mi++)
        kf[mi] = *(const short8*)&KVd[buf][ks * 2048 + mi * 512 + lane * 8];
#pragma unroll
      for (int mi = 0; mi < 4; mi++)
#pragma unroll
        for (int nj = 0; nj < 2; nj++)
          st[mi][nj] = __builtin_amdgcn_mfma_f32_16x16x32_bf16(kf[mi], qf[nj][ks], st[mi][nj], 0, 0, 0);
    }

    uint2 pka[4][2];
#pragma unroll
    for (int mi = 0; mi < 4; mi++)
#pragma unroll
      for (int nj = 0; nj < 2; nj++) {
        float p0 = EXP2(st[mi][nj][0]);
        float p1 = EXP2(st[mi][nj][1]);
        float p2 = EXP2(st[mi][nj][2]);
        float p3 = EXP2(st[mi][nj][3]);
        pka[mi][nj].x = pk2(p0, p1);
        pka[mi][nj].y = pk2(p2, p3);
      }

#pragma unroll
    for (int kp = 0; kp < 2; kp++) {
      short8 vf[4];
#pragma unroll
      for (int ci = 0; ci < 4; ci++)
        vf[ci] = *(const short8*)&KVd[buf][4096 + kp * 2048 + ci * 512 + lane * 8];
#pragma unroll
      for (int ri = 0; ri < 2; ri++) {
        union { uint4 u; short8 s; } a;
        a.u.x = pka[2 * kp][ri].x;
        a.u.y = pka[2 * kp][ri].y;
        a.u.z = pka[2 * kp + 1][ri].x;
        a.u.w = pka[2 * kp + 1][ri].y;
#pragma unroll
        for (int ci = 0; ci < 4; ci++)
          o[ri][ci] = __builtin_amdgcn_mfma_f32_16x16x32_bf16(a.s, vf[ci], o[ri][ci], 0, 0, 0);
        ol[ri] = __builtin_amdgcn_mfma_f32_16x16x32_bf16(a.s, ones, ol[ri], 0, 0, 0);
      }
    }

    __syncthreads();
  }

  const int b = bh >> 4, h = bh & 15;
#pragma unroll
  for (int ri = 0; ri < 2; ri++)
#pragma unroll
    for (int r = 0; r < 4; r++) {
      const float inv = 1.0f / ol[ri][r];
      const int n = q0 + wave * 32 + ri * 16 + q * 4 + r;
#pragma unroll
      for (int ci = 0; ci < 4; ci++) {
        const int d = ci * 16 + r16;
        Ob[((size_t)(b * NN + n)) * EE + h * 64 + d] = f2bf(o[ri][ci][r] * inv);
      }
    }
}

// ---------------- launch ----------------

extern "C" void kernel_launch(void* const* d_in, const int* in_sizes, int n_in,
                              void* d_out, int out_size, void* d_ws, size_t ws_size,
                              hipStream_t stream) {
  const float* x     = (const float*)d_in[0];
  const float* Wqkv  = (const float*)d_in[1];
  const float* bqkv  = (const float*)d_in[2];
  const float* Wproj = (const float*)d_in[3];
  const float* bproj = (const float*)d_in[4];
  float* out = (float*)d_out;
  char* ws = (char*)d_ws;

  u16* Xb     = (u16*)(ws);                      // 16MB (aliased by Ob after gemm_qkv)
  u16* Ob     = Xb;
  u16* Qb     = (u16*)(ws + (size_t)(16 << 20)); // 16MB (pre-scaled by CS)
  u16* KVt    = (u16*)(ws + (size_t)(32 << 20)); // 32MB merged K/V chunk layout
  u16* WqkvT  = (u16*)(ws + (size_t)(64 << 20)); // 6MB   [c'][k]
  u16* WprojT = (u16*)(ws + (size_t)(72 << 20)); // 2MB   [e_out][e_in]

  prep_kernel<<<12288, 256, 0, stream>>>(x, Xb, Wqkv, WqkvT, Wproj, WprojT);
  gemm_qkv<<<dim3(12, 32), 512, 0, stream>>>(Xb, WqkvT, bqkv, Qb, KVt);
  attn_kernel<<<dim3(16, 64), 256, 0, stream>>>(Qb, KVt, Ob);
  gemm_proj<<<dim3(4, 32), 512, 0, stream>>>(Ob, WprojT, bproj, out);
}

// Round 5
// 308.375 us; speedup vs baseline: 1.0217x; 1.0217x over previous
//
#include <hip/hip_runtime.h>
#include <stdint.h>

typedef unsigned short u16;
typedef __attribute__((ext_vector_type(8))) short short8;   // 8 bf16 = 4 VGPRs
typedef __attribute__((ext_vector_type(4))) float f32x4;

#define LOG2E 1.44269504088896340736f
#define CS (0.03125f * LOG2E)   // softmax scale 1/sqrt(E)=1/32, folded into exp2 domain
// Problem dims
#define BB 4
#define NN 2048
#define EE 1024
#define HH 16
#define DD 64
#define MM 8192   // B*N
#define C3 3072   // 3*E

#if __has_builtin(__builtin_amdgcn_exp2f)
#define EXP2(x) __builtin_amdgcn_exp2f(x)
#else
#define EXP2(x) exp2f(x)
#endif

__device__ __forceinline__ u16 f2bf(float f) {
  union { float f; unsigned u; } v; v.f = f;
  unsigned r = v.u + 0x7fffu + ((v.u >> 16) & 1u);
  return (u16)(r >> 16);
}

#if __has_builtin(__builtin_amdgcn_cvt_pk_bf16_f32)
typedef __attribute__((ext_vector_type(2))) __bf16 bf16x2;
__device__ __forceinline__ unsigned pk2(float a, float b) {
  union { bf16x2 v; unsigned u; } c;
  c.v = __builtin_amdgcn_cvt_pk_bf16_f32(a, b);
  return c.u;
}
#else
__device__ __forceinline__ unsigned pk2(float a, float b) {
  union { float f; unsigned u; } x, y; x.f = a; y.f = b;
  return ((x.u + 0x8000u) >> 16) | ((y.u + 0x8000u) & 0xffff0000u);
}
#endif

__device__ __forceinline__ void async16(const void* g, void* l) {
  __builtin_amdgcn_global_load_lds((const __attribute__((address_space(1))) void*)g,
                                   (__attribute__((address_space(3))) void*)l,
                                   16, 0, 0);
}

// in-tile V key permutation (matches in-register P fragment assembly):
// stored slot s from true key t (6 bits): s = (t5, t3, t2, t4, t1, t0)
__device__ __forceinline__ int vperm(int t) {
  return (t & 0x23) | ((t & 8) << 1) | ((t & 4) << 1) | ((t & 16) >> 2);
}

// ---------------- fused prep kernel ----------------
__global__ __launch_bounds__(256) void prep_kernel(const float* __restrict__ x, u16* __restrict__ xb,
                                                   const float* __restrict__ Wqkv, u16* __restrict__ WqkvT,
                                                   const float* __restrict__ Wproj, u16* __restrict__ WprojT) {
  __shared__ float tile[32][33];
  const int bid = blockIdx.x;
  if (bid < 8192) {
    int i = (bid * 256 + threadIdx.x) * 4;
    float4 v = *(const float4*)(x + i);
    ushort4 o; o.x = f2bf(v.x); o.y = f2bf(v.y); o.z = f2bf(v.z); o.w = f2bf(v.w);
    *(ushort4*)(xb + i) = o;
    return;
  }
  const int permute = bid < 11264 ? 1 : 0;
  const float* W = permute ? Wqkv : Wproj;
  u16* Wt = permute ? WqkvT : WprojT;
  const int ncols = permute ? C3 : EE;
  const int t = permute ? bid - 8192 : bid - 11264;
  const int nbx = permute ? 96 : 32;
  const int c0 = (t % nbx) * 32, k0 = (t / nbx) * 32;
  const int tx = threadIdx.x & 31, ty = threadIdx.x >> 5;  // ty 0..7
#pragma unroll
  for (int r = 0; r < 32; r += 8)
    tile[ty + r][tx] = W[(size_t)(k0 + ty + r) * ncols + c0 + tx];
  __syncthreads();
#pragma unroll
  for (int r = 0; r < 32; r += 8) {
    int c = c0 + ty + r;
    int cp = c;
    if (permute) {
      int tt = c % 3, hh = c / 192, d = (c / 3) % 64;
      cp = tt * 1024 + hh * 64 + d;
    }
    Wt[(size_t)cp * EE + k0 + tx] = f2bf(tile[tx][ty + r]);
  }
}

// ---------------- GEMM core (R1 2-phase structure + chunk-order LDS) ----------------
// 128x128 tile, BK=64, 4 waves (2M x 2N), per-wave 64x64 (4x4 frags).
// REVERTED from the 8-phase/counted-vmcnt experiments (R2: 106us, R4: 100us vs
// this structure's 80us) -- at 1 block/CU the deep pipeline loses all implicit
// cross-block wave overlap (m114) and stalls at barriers (VALUBusy 10%).
// NEW vs R1: LDS is in CHUNK ORDER -- chunk id = ((ks*2+w)*4+f)*64+lane, so
// every ds_read_b128 is const + lane*16B (identity -> zero bank conflicts;
// R1 measured 6.29M conflict cycles with the [row][32] subtile layout).
// Global source is per-lane scattered to compensate (both-sides-or-neither);
// per-instruction coalescing is unchanged (16 rows x 64B segments).
template <int KDIM>
__device__ __forceinline__ void gemm_core(const u16* __restrict__ A, const u16* __restrict__ Bt,
                                          int m0, int n0, u16* As, u16* Bs, f32x4 acc[4][4]) {
  const int tid = threadIdx.x;
  const int lane = tid & 63, wave = tid >> 6;
  const int wm = wave >> 1, wn = wave & 1;
#pragma unroll
  for (int i = 0; i < 4; i++)
#pragma unroll
    for (int j = 0; j < 4; j++) acc[i][j] = (f32x4){0.f, 0.f, 0.f, 0.f};

  const u16* Abase = A + (size_t)m0 * KDIM;
  const u16* Bbase = Bt + (size_t)n0 * KDIM;

  for (int k0 = 0; k0 < KDIM; k0 += 64) {
    // stage A-tile: 1024 chunks of 16B; chunk c = ((ks*2+w)*4+f)*64 + l
    // holds (row = w*64+f*16+(l&15), k = ks*32+(l>>4)*8)
#pragma unroll
    for (int i = 0; i < 4; i++) {
      int c = i * 256 + tid;
      int l = c & 63, f = (c >> 6) & 3, w = (c >> 8) & 1, ks = (c >> 9) & 1;
      int row = w * 64 + f * 16 + (l & 15);
      int k = ks * 32 + (l >> 4) * 8;
      async16(Abase + (size_t)row * KDIM + k0 + k, &As[c * 8]);
    }
#pragma unroll
    for (int i = 0; i < 4; i++) {
      int c = i * 256 + tid;
      int l = c & 63, f = (c >> 6) & 3, w = (c >> 8) & 1, ks = (c >> 9) & 1;
      int row = w * 64 + f * 16 + (l & 15);
      int k = ks * 32 + (l >> 4) * 8;
      async16(Bbase + (size_t)row * KDIM + k0 + k, &Bs[c * 8]);
    }
    __syncthreads();
#pragma unroll
    for (int ks = 0; ks < 2; ks++) {
      short8 af[4], bf[4];
#pragma unroll
      for (int i = 0; i < 4; i++)
        af[i] = *(const short8*)&As[(((ks * 2 + wm) * 4 + i) * 64 + lane) * 8];
#pragma unroll
      for (int i = 0; i < 4; i++)
        bf[i] = *(const short8*)&Bs[(((ks * 2 + wn) * 4 + i) * 64 + lane) * 8];
#pragma unroll
      for (int i = 0; i < 4; i++)
#pragma unroll
        for (int j = 0; j < 4; j++)
          acc[i][j] = __builtin_amdgcn_mfma_f32_16x16x32_bf16(af[i], bf[j], acc[i][j], 0, 0, 0);
    }
    __syncthreads();
  }
}

// ---------------- merged K/V chunk layout ----------------
// KVt[bh][tile(32)][8192 u16]:
//   first 4096  = K-tile chunks: idx = ks*2048 + mi*512 + (q*16+r16)*8 + e
//   second 4096 = V-tile chunks: idx = kp*2048 + ci*512 + (q*16+r16)*8 + e
//                 (V key-slots permuted by vperm)

// QKV GEMM: X[8192,1024] @ WqkvT -> Q(pre-scaled by CS) to [bh][n][d], K/V to KVt chunks
__global__ __launch_bounds__(256) void gemm_qkv(const u16* __restrict__ Xb, const u16* __restrict__ Wt,
                                                const float* __restrict__ bqkv, u16* __restrict__ Qb,
                                                u16* __restrict__ KVt) {
  __shared__ __align__(16) u16 As[128 * 64];
  __shared__ __align__(16) u16 Bs[128 * 64];
  f32x4 acc[4][4];
  const int m0 = blockIdx.y * 128, n0 = blockIdx.x * 128;
  gemm_core<EE>(Xb, Wt, m0, n0, As, Bs, acc);
  const int tid = threadIdx.x, lane = tid & 63, wave = tid >> 6;
  const int q = lane >> 4, r16 = lane & 15;
  const int wrow = (wave >> 1) * 64, wcol = (wave & 1) * 64;
  // each 128-col block lies entirely in one t-region (Q, K, or V)
  const int t = (n0 + wcol) >> 10;
  const int b = (m0 + wrow) >> 11;          // wave-uniform batch
#pragma unroll
  for (int ci = 0; ci < 4; ci++) {
    const int cp = n0 + wcol + ci * 16 + r16;  // permuted col: t*1024 + h*64 + d
    const int hh = (cp >> 6) & 15, d = cp & 63;
    const float bias = bqkv[hh * 192 + d * 3 + t];  // bias permute folded in
    if (t == 0) {
#pragma unroll
      for (int ri = 0; ri < 4; ri++)
#pragma unroll
        for (int r = 0; r < 4; r++) {
          const int m = m0 + wrow + ri * 16 + q * 4 + r;
          Qb[((size_t)(b * 16 + hh) * 2048 + (m & 2047)) * 64 + d] = f2bf((acc[ri][ci][r] + bias) * CS);
        }
    } else if (t == 1) {
      // K -> chunk layout: (key,d) -> tile*8192 + (d>>5)*2048 + (key>>4&3)*512
      //                                + (d>>3&3)*128 + (key&15)*8 + (d&7)
      const size_t bhbase = (size_t)(b * 16 + hh) * 32;
      const size_t dpart = (size_t)(d >> 5) * 2048 + ((d >> 3) & 3) * 128 + (d & 7);
#pragma unroll
      for (int ri = 0; ri < 4; ri++)
#pragma unroll
        for (int r = 0; r < 4; r++) {
          const int key = (m0 + wrow + ri * 16 + q * 4 + r) & 2047;
          KVt[(bhbase + (key >> 6)) * 8192 + dpart + ((key >> 4) & 3) * 512 + (key & 15) * 8] =
              f2bf(acc[ri][ci][r] + bias);
        }
    } else {
      // V: C rows (quad*4+reg) are 4 consecutive true keys; vperm preserves low
      // 2 bits so the 4 slots stay contiguous -> 8B store at the chunk address
      const size_t bhbase = (size_t)(b * 16 + hh) * 32;
      const int dpart = (d >> 4) * 512 + (d & 15) * 8;
#pragma unroll
      for (int ri = 0; ri < 4; ri++) {
        const int nb = (m0 + wrow + ri * 16 + q * 4) & 2047;
        const int sb = vperm(nb & 63);  // 4-aligned -> 4-contiguous preserved
        ushort4 w;
        w.x = f2bf(acc[ri][ci][0] + bias);
        w.y = f2bf(acc[ri][ci][1] + bias);
        w.z = f2bf(acc[ri][ci][2] + bias);
        w.w = f2bf(acc[ri][ci][3] + bias);
        *(ushort4*)&KVt[(bhbase + (nb >> 6)) * 8192 + 4096 + (sb >> 5) * 2048 +
                        ((sb >> 3) & 3) * 128 + dpart + (sb & 7)] = w;
      }
    }
  }
}

// Proj GEMM: O[8192,1024] @ WprojT + bproj -> fp32 out
__global__ __launch_bounds__(256) void gemm_proj(const u16* __restrict__ Ob, const u16* __restrict__ Wt,
                                                 const float* __restrict__ bp, float* __restrict__ out) {
  __shared__ __align__(16) u16 As[128 * 64];
  __shared__ __align__(16) u16 Bs[128 * 64];
  f32x4 acc[4][4];
  const int m0 = blockIdx.y * 128, n0 = blockIdx.x * 128;
  gemm_core<EE>(Ob, Wt, m0, n0, As, Bs, acc);
  const int tid = threadIdx.x, lane = tid & 63, wave = tid >> 6;
  const int q = lane >> 4, r16 = lane & 15;
  const int wrow = (wave >> 1) * 64, wcol = (wave & 1) * 64;
#pragma unroll
  for (int ci = 0; ci < 4; ci++) {
    const int col = n0 + wcol + ci * 16 + r16;
    const float bias = bp[col];
#pragma unroll
    for (int ri = 0; ri < 4; ri++)
#pragma unroll
      for (int r = 0; r < 4; r++) {
        const int m = m0 + wrow + ri * 16 + q * 4 + r;
        out[(size_t)m * EE + col] = acc[ri][ci][r] + bias;
      }
  }
}

// ---------------- flash attention (R1 version: chunk-order LDS, conflicts = 0) ----------------
__global__ __launch_bounds__(256, 4) void attn_kernel(const u16* __restrict__ Qg, const u16* __restrict__ KVg,
                                                      u16* __restrict__ Ob) {
  __shared__ __align__(16) u16 KVd[2][8192];  // [buf][K:4096 | V:4096] chunk-ordered
  const int tid = threadIdx.x, lane = tid & 63, wave = tid >> 6;
  const int q = lane >> 4, r16 = lane & 15;
  // XCD swizzle: id%8 presumed XCD; give each bh a fixed XCD
  const int id = blockIdx.x + 16 * blockIdx.y;
  const int g = id & 7, s = id >> 3;
  const int bh = g * 8 + (s >> 4);
  const int q0 = (s & 15) * 128;
  const u16* Qp = Qg + ((size_t)bh * NN + q0) * DD;
  const u16* KVp = KVg + (size_t)bh * (32 * 8192);

  // Q fragments straight from global (B-operand layout: row=r16, k=q*8+j)
  short8 qf[2][2];  // [nj][ks]
#pragma unroll
  for (int nj = 0; nj < 2; nj++)
#pragma unroll
    for (int ks = 0; ks < 2; ks++)
      qf[nj][ks] = *(const short8*)(Qp + (wave * 32 + nj * 16 + r16) * 64 + ks * 32 + q * 8);

  // stage K/V tile 0 into buf 0 (pure linear copy: 1024 chunks x 16B)
#pragma unroll
  for (int i = 0; i < 4; i++) {
    int c = i * 256 + tid;
    async16(KVp + c * 8, &KVd[0][c * 8]);
  }
  __syncthreads();  // tile0 landed

  f32x4 o[2][4];    // O accumulator [ri][ci]
  f32x4 ol[2];      // row-sum accumulator via ones-MFMA
#pragma unroll
  for (int i = 0; i < 2; i++) {
    ol[i] = (f32x4){0.f, 0.f, 0.f, 0.f};
#pragma unroll
    for (int j = 0; j < 4; j++) o[i][j] = (f32x4){0.f, 0.f, 0.f, 0.f};
  }
  const short8 ones = {16256, 16256, 16256, 16256, 16256, 16256, 16256, 16256};  // bf16 1.0

  for (int j = 0; j < 32; j++) {
    const int buf = j & 1;
    // prefetch tile j+1 into the other buffer (overlaps with compute below)
    if (j < 31) {
      const u16* src = KVp + (size_t)(j + 1) * 8192;
#pragma unroll
      for (int i = 0; i < 4; i++) {
        int c = i * 256 + tid;
        async16(src + c * 8, &KVd[buf ^ 1][c * 8]);
      }
    }

    // S^T = K.Q^T : st[mi][nj]; m = keys, n = q-rows (already in exp2 domain)
    f32x4 st[4][2];
#pragma unroll
    for (int mi = 0; mi < 4; mi++)
#pragma unroll
      for (int nj = 0; nj < 2; nj++) st[mi][nj] = (f32x4){0.f, 0.f, 0.f, 0.f};
#pragma unroll
    for (int ks = 0; ks < 2; ks++) {
      short8 kf[4];
#pragma unroll
      for (int mi = 0; mi < 4; mi++)
        kf[mi] = *(const short8*)&KVd[buf][ks * 2048 + mi * 512 + lane * 8];
#pragma unroll
      for (int mi = 0; mi < 4; mi++)
#pragma unroll
        for (int nj = 0; nj < 2; nj++)
          st[mi][nj] = __builtin_amdgcn_mfma_f32_16x16x32_bf16(kf[mi], qf[nj][ks], st[mi][nj], 0, 0, 0);
    }

    // p = exp2(s'); pack in-register (keys stay lane-local; no LDS round-trip)
    uint2 pka[4][2];  // [mi][nj] = (pk(r0,r1), pk(r2,r3))
#pragma unroll
    for (int mi = 0; mi < 4; mi++)
#pragma unroll
      for (int nj = 0; nj < 2; nj++) {
        float p0 = EXP2(st[mi][nj][0]);
        float p1 = EXP2(st[mi][nj][1]);
        float p2 = EXP2(st[mi][nj][2]);
        float p3 = EXP2(st[mi][nj][3]);
        pka[mi][nj].x = pk2(p0, p1);
        pka[mi][nj].y = pk2(p2, p3);
      }

    // O += P.V ; row-sums += P.1  (A-frags assembled in-register)
#pragma unroll
    for (int kp = 0; kp < 2; kp++) {
      short8 vf[4];
#pragma unroll
      for (int ci = 0; ci < 4; ci++)
        vf[ci] = *(const short8*)&KVd[buf][4096 + kp * 2048 + ci * 512 + lane * 8];
#pragma unroll
      for (int ri = 0; ri < 2; ri++) {
        union { uint4 u; short8 s; } a;
        a.u.x = pka[2 * kp][ri].x;
        a.u.y = pka[2 * kp][ri].y;
        a.u.z = pka[2 * kp + 1][ri].x;
        a.u.w = pka[2 * kp + 1][ri].y;
#pragma unroll
        for (int ci = 0; ci < 4; ci++)
          o[ri][ci] = __builtin_amdgcn_mfma_f32_16x16x32_bf16(a.s, vf[ci], o[ri][ci], 0, 0, 0);
        ol[ri] = __builtin_amdgcn_mfma_f32_16x16x32_bf16(a.s, ones, ol[ri], 0, 0, 0);
      }
    }

    __syncthreads();  // drains prefetch (issued a full compute phase ago); buffer handoff
  }

  // epilogue: O/l -> Ob[b][n][h*64+d] bf16; no reduction needed (ones-trick)
  const int b = bh >> 4, h = bh & 15;
#pragma unroll
  for (int ri = 0; ri < 2; ri++)
#pragma unroll
    for (int r = 0; r < 4; r++) {
      const float inv = 1.0f / ol[ri][r];
      const int n = q0 + wave * 32 + ri * 16 + q * 4 + r;
#pragma unroll
      for (int ci = 0; ci < 4; ci++) {
        const int d = ci * 16 + r16;
        Ob[((size_t)(b * NN + n)) * EE + h * 64 + d] = f2bf(o[ri][ci][r] * inv);
      }
    }
}

// ---------------- launch ----------------

extern "C" void kernel_launch(void* const* d_in, const int* in_sizes, int n_in,
                              void* d_out, int out_size, void* d_ws, size_t ws_size,
                              hipStream_t stream) {
  const float* x     = (const float*)d_in[0];
  const float* Wqkv  = (const float*)d_in[1];
  const float* bqkv  = (const float*)d_in[2];
  const float* Wproj = (const float*)d_in[3];
  const float* bproj = (const float*)d_in[4];
  float* out = (float*)d_out;
  char* ws = (char*)d_ws;

  u16* Xb     = (u16*)(ws);                      // 16MB (aliased by Ob after gemm_qkv)
  u16* Ob     = Xb;
  u16* Qb     = (u16*)(ws + (size_t)(16 << 20)); // 16MB (pre-scaled by CS)
  u16* KVt    = (u16*)(ws + (size_t)(32 << 20)); // 32MB merged K/V chunk layout
  u16* WqkvT  = (u16*)(ws + (size_t)(64 << 20)); // 6MB   [c'][k]
  u16* WprojT = (u16*)(ws + (size_t)(72 << 20)); // 2MB   [e_out][e_in]

  prep_kernel<<<12288, 256, 0, stream>>>(x, Xb, Wqkv, WqkvT, Wproj, WprojT);
  gemm_qkv<<<dim3(24, 64), 256, 0, stream>>>(Xb, WqkvT, bqkv, Qb, KVt);
  attn_kernel<<<dim3(16, 64), 256, 0, stream>>>(Qb, KVt, Ob);
  gemm_proj<<<dim3(8, 64), 256, 0, stream>>>(Ob, WprojT, bproj, out);
}

// Round 6
// 266.854 us; speedup vs baseline: 1.1806x; 1.1556x over previous
//
#include <hip/hip_runtime.h>
#include <stdint.h>

typedef unsigned short u16;
typedef __attribute__((ext_vector_type(8))) short short8;   // 8 bf16 = 4 VGPRs
typedef __attribute__((ext_vector_type(4))) float f32x4;

#define LOG2E 1.44269504088896340736f
#define CS (0.03125f * LOG2E)   // softmax scale 1/sqrt(E)=1/32, folded into exp2 domain
// Problem dims
#define BB 4
#define NN 2048
#define EE 1024
#define HH 16
#define DD 64
#define MM 8192   // B*N
#define C3 3072   // 3*E

#if __has_builtin(__builtin_amdgcn_exp2f)
#define EXP2(x) __builtin_amdgcn_exp2f(x)
#else
#define EXP2(x) exp2f(x)
#endif

__device__ __forceinline__ u16 f2bf(float f) {
  union { float f; unsigned u; } v; v.f = f;
  unsigned r = v.u + 0x7fffu + ((v.u >> 16) & 1u);
  return (u16)(r >> 16);
}

#if __has_builtin(__builtin_amdgcn_cvt_pk_bf16_f32)
typedef __attribute__((ext_vector_type(2))) __bf16 bf16x2;
__device__ __forceinline__ unsigned pk2(float a, float b) {
  union { bf16x2 v; unsigned u; } c;
  c.v = __builtin_amdgcn_cvt_pk_bf16_f32(a, b);
  return c.u;
}
#else
__device__ __forceinline__ unsigned pk2(float a, float b) {
  union { float f; unsigned u; } x, y; x.f = a; y.f = b;
  return ((x.u + 0x8000u) >> 16) | ((y.u + 0x8000u) & 0xffff0000u);
}
#endif

__device__ __forceinline__ void async16(const void* g, void* l) {
  __builtin_amdgcn_global_load_lds((const __attribute__((address_space(1))) void*)g,
                                   (__attribute__((address_space(3))) void*)l,
                                   16, 0, 0);
}

// in-tile V key permutation (matches in-register P fragment assembly):
// stored slot s from true key t (6 bits): s = (t5, t3, t2, t4, t1, t0)
__device__ __forceinline__ int vperm(int t) {
  return (t & 0x23) | ((t & 8) << 1) | ((t & 4) << 1) | ((t & 16) >> 2);
}

// ---------------- fused prep kernel ----------------
// blocks [0,8192): cast x fp32->bf16
// blocks [8192,11264): transpose+cast+permute Wqkv -> WqkvT[cp][k]
// blocks [11264,12288): transpose+cast Wproj -> WprojT[c][k]
__global__ __launch_bounds__(256) void prep_kernel(const float* __restrict__ x, u16* __restrict__ xb,
                                                   const float* __restrict__ Wqkv, u16* __restrict__ WqkvT,
                                                   const float* __restrict__ Wproj, u16* __restrict__ WprojT) {
  __shared__ float tile[32][33];
  const int bid = blockIdx.x;
  if (bid < 8192) {
    int i = (bid * 256 + threadIdx.x) * 4;
    float4 v = *(const float4*)(x + i);
    ushort4 o; o.x = f2bf(v.x); o.y = f2bf(v.y); o.z = f2bf(v.z); o.w = f2bf(v.w);
    *(ushort4*)(xb + i) = o;
    return;
  }
  const int permute = bid < 11264 ? 1 : 0;
  const float* W = permute ? Wqkv : Wproj;
  u16* Wt = permute ? WqkvT : WprojT;
  const int ncols = permute ? C3 : EE;
  const int t = permute ? bid - 8192 : bid - 11264;
  const int nbx = permute ? 96 : 32;
  const int c0 = (t % nbx) * 32, k0 = (t / nbx) * 32;
  const int tx = threadIdx.x & 31, ty = threadIdx.x >> 5;  // ty 0..7
#pragma unroll
  for (int r = 0; r < 32; r += 8)
    tile[ty + r][tx] = W[(size_t)(k0 + ty + r) * ncols + c0 + tx];
  __syncthreads();
#pragma unroll
  for (int r = 0; r < 32; r += 8) {
    int c = c0 + ty + r;
    int cp = c;
    if (permute) {
      int tt = c % 3, hh = c / 192, d = (c / 3) % 64;
      cp = tt * 1024 + hh * 64 + d;
    }
    Wt[(size_t)cp * EE + k0 + tx] = f2bf(tile[tx][ty + r]);
  }
}

// ---------------- GEMM core (R1 structure: BK=64, A[M,K] @ Bt[N,K]) ----------------
// RESTORED to the R1-measured-best form (80us, 644 TF = the m248 2-phase K=1024
// ceiling). LDS tiles as [ks2][row128][32] sub-tiles: 64B row stride. The ~8-way
// read conflicts (6.3M cycles) are ACCEPTED: at the 2-phase structure they are
// off the critical path (m252 regime-gate; R5 proved removing them via chunk-
// order LDS costs 40% because the scattered global SOURCE breaks per-quad VMEM
// coalescing -- consecutive lanes must read contiguous 64B for global_load_lds).
// 8-phase/256-sq routes are closed for this problem: qkv grid at 256-sq = 384
// blocks = 1.5/CU (75% balance ceiling) and proj = 128 blocks = 0.5/CU.
template <int KDIM>
__device__ __forceinline__ void gemm_core(const u16* __restrict__ A, const u16* __restrict__ Bt,
                                          int m0, int n0, u16* As, u16* Bs, f32x4 acc[4][4]) {
  const int tid = threadIdx.x;
  const int lane = tid & 63, wave = tid >> 6;
  const int q = lane >> 4, r16 = lane & 15;
  const int wrow = (wave >> 1) * 64, wcol = (wave & 1) * 64;
#pragma unroll
  for (int i = 0; i < 4; i++)
#pragma unroll
    for (int j = 0; j < 4; j++) acc[i][j] = (f32x4){0.f, 0.f, 0.f, 0.f};

  for (int k0 = 0; k0 < KDIM; k0 += 64) {
#pragma unroll
    for (int i = 0; i < 4; i++) {
      int c = i * 256 + tid;  // 0..1023: ks = c>>9, row = (c&511)>>2, k8 = c&3
      int ks = c >> 9, rem = c & 511, row = rem >> 2, k8 = rem & 3;
      async16(A + (size_t)(m0 + row) * KDIM + k0 + ks * 32 + k8 * 8, &As[c * 8]);
    }
#pragma unroll
    for (int i = 0; i < 4; i++) {
      int c = i * 256 + tid;
      int ks = c >> 9, rem = c & 511, row = rem >> 2, k8 = rem & 3;
      async16(Bt + (size_t)(n0 + row) * KDIM + k0 + ks * 32 + k8 * 8, &Bs[c * 8]);
    }
    __syncthreads();
#pragma unroll
    for (int ks = 0; ks < 2; ks++) {
      short8 af[4], bf[4];
#pragma unroll
      for (int i = 0; i < 4; i++)
        af[i] = *(const short8*)&As[ks * 4096 + (wrow + i * 16 + r16) * 32 + q * 8];
#pragma unroll
      for (int i = 0; i < 4; i++)
        bf[i] = *(const short8*)&Bs[ks * 4096 + (wcol + i * 16 + r16) * 32 + q * 8];
#pragma unroll
      for (int i = 0; i < 4; i++)
#pragma unroll
        for (int j = 0; j < 4; j++)
          acc[i][j] = __builtin_amdgcn_mfma_f32_16x16x32_bf16(af[i], bf[j], acc[i][j], 0, 0, 0);
    }
    __syncthreads();
  }
}

// ---------------- merged K/V chunk layout ----------------
// KVt[bh][tile(32)][8192 u16]:
//   first 4096  = K-tile chunks: idx = ks*2048 + mi*512 + (q*16+r16)*8 + e
//                 holding (key = mi*16+r16, d = ks*32+q*8+e)
//   second 4096 = V-tile chunks: idx = kp*2048 + ci*512 + (q*16+r16)*8 + e
//                 holding (d = ci*16+r16, slot s = kp*32+q*8+e)  [s = vperm(true key)]
// Written by gemm_qkv's epilogue, so attn's staging is a PURE LINEAR copy
// (coalesced global reads AND identity LDS -> zero bank conflicts).

// QKV GEMM: X[8192,1024] @ WqkvT -> Q(pre-scaled by CS) to [bh][n][d], K/V to KVt chunks
__global__ __launch_bounds__(256) void gemm_qkv(const u16* __restrict__ Xb, const u16* __restrict__ Wt,
                                                const float* __restrict__ bqkv, u16* __restrict__ Qb,
                                                u16* __restrict__ KVt) {
  __shared__ __align__(16) u16 As[128 * 64];
  __shared__ __align__(16) u16 Bs[128 * 64];
  f32x4 acc[4][4];
  const int m0 = blockIdx.y * 128, n0 = blockIdx.x * 128;
  gemm_core<EE>(Xb, Wt, m0, n0, As, Bs, acc);
  const int tid = threadIdx.x, lane = tid & 63, wave = tid >> 6;
  const int q = lane >> 4, r16 = lane & 15;
  const int wrow = (wave >> 1) * 64, wcol = (wave & 1) * 64;
  // each 128-col block lies entirely in one t-region (Q, K, or V)
  const int t = (n0 + wcol) >> 10;
  const int b = (m0 + wrow) >> 11;          // wave-uniform batch
#pragma unroll
  for (int ci = 0; ci < 4; ci++) {
    const int cp = n0 + wcol + ci * 16 + r16;  // permuted col: t*1024 + h*64 + d
    const int hh = (cp >> 6) & 15, d = cp & 63;
    const float bias = bqkv[hh * 192 + d * 3 + t];  // bias permute folded in
    if (t == 0) {
#pragma unroll
      for (int ri = 0; ri < 4; ri++)
#pragma unroll
        for (int r = 0; r < 4; r++) {
          const int m = m0 + wrow + ri * 16 + q * 4 + r;
          Qb[((size_t)(b * 16 + hh) * 2048 + (m & 2047)) * 64 + d] = f2bf((acc[ri][ci][r] + bias) * CS);
        }
    } else if (t == 1) {
      // K -> chunk layout: (key,d) -> tile*8192 + (d>>5)*2048 + (key>>4&3)*512
      //                                + (d>>3&3)*128 + (key&15)*8 + (d&7)
      const size_t bhbase = (size_t)(b * 16 + hh) * 32;
      const size_t dpart = (size_t)(d >> 5) * 2048 + ((d >> 3) & 3) * 128 + (d & 7);
#pragma unroll
      for (int ri = 0; ri < 4; ri++)
#pragma unroll
        for (int r = 0; r < 4; r++) {
          const int key = (m0 + wrow + ri * 16 + q * 4 + r) & 2047;
          KVt[(bhbase + (key >> 6)) * 8192 + dpart + ((key >> 4) & 3) * 512 + (key & 15) * 8] =
              f2bf(acc[ri][ci][r] + bias);
        }
    } else {
      // V: C rows (quad*4+reg) are 4 consecutive true keys; vperm preserves low
      // 2 bits so the 4 slots stay contiguous -> 8B store at the chunk address
      const size_t bhbase = (size_t)(b * 16 + hh) * 32;
      const int dpart = (d >> 4) * 512 + (d & 15) * 8;
#pragma unroll
      for (int ri = 0; ri < 4; ri++) {
        const int nb = (m0 + wrow + ri * 16 + q * 4) & 2047;
        const int sb = vperm(nb & 63);  // 4-aligned -> 4-contiguous preserved
        ushort4 w;
        w.x = f2bf(acc[ri][ci][0] + bias);
        w.y = f2bf(acc[ri][ci][1] + bias);
        w.z = f2bf(acc[ri][ci][2] + bias);
        w.w = f2bf(acc[ri][ci][3] + bias);
        *(ushort4*)&KVt[(bhbase + (nb >> 6)) * 8192 + 4096 + (sb >> 5) * 2048 +
                        ((sb >> 3) & 3) * 128 + dpart + (sb & 7)] = w;
      }
    }
  }
}

// Proj GEMM: O[8192,1024] @ WprojT + bproj -> fp32 out
__global__ __launch_bounds__(256) void gemm_proj(const u16* __restrict__ Ob, const u16* __restrict__ Wt,
                                                 const float* __restrict__ bp, float* __restrict__ out) {
  __shared__ __align__(16) u16 As[128 * 64];
  __shared__ __align__(16) u16 Bs[128 * 64];
  f32x4 acc[4][4];
  const int m0 = blockIdx.y * 128, n0 = blockIdx.x * 128;
  gemm_core<EE>(Ob, Wt, m0, n0, As, Bs, acc);
  const int tid = threadIdx.x, lane = tid & 63, wave = tid >> 6;
  const int q = lane >> 4, r16 = lane & 15;
  const int wrow = (wave >> 1) * 64, wcol = (wave & 1) * 64;
#pragma unroll
  for (int ci = 0; ci < 4; ci++) {
    const int col = n0 + wcol + ci * 16 + r16;
    const float bias = bp[col];
#pragma unroll
    for (int ri = 0; ri < 4; ri++)
#pragma unroll
      for (int r = 0; r < 4; r++) {
        const int m = m0 + wrow + ri * 16 + q * 4 + r;
        out[(size_t)m * EE + col] = acc[ri][ci][r] + bias;
      }
  }
}

// ---------------- flash attention (R1 chunk-order LDS, conflicts = 0; + T5 setprio) ----------------
// P never touches LDS: the PV contraction is key-permutation invariant, so the
// A-fragment is assembled IN-REGISTER from each lane's own packed exp2 outputs;
// K/V staging is a LINEAR copy and every ds_read_b128 is const + lane*16B.
// LDS = 32KB -> 4 blocks/CU. setprio(1) wraps the MFMA clusters: attn's waves
// are phase-diverse (only 1 barrier/tile), the m191-positive regime for T5.
__global__ __launch_bounds__(256, 4) void attn_kernel(const u16* __restrict__ Qg, const u16* __restrict__ KVg,
                                                      u16* __restrict__ Ob) {
  __shared__ __align__(16) u16 KVd[2][8192];  // [buf][K:4096 | V:4096] chunk-ordered
  const int tid = threadIdx.x, lane = tid & 63, wave = tid >> 6;
  const int q = lane >> 4, r16 = lane & 15;
  // XCD swizzle: id%8 presumed XCD; give each bh a fixed XCD
  const int id = blockIdx.x + 16 * blockIdx.y;
  const int g = id & 7, s = id >> 3;
  const int bh = g * 8 + (s >> 4);
  const int q0 = (s & 15) * 128;
  const u16* Qp = Qg + ((size_t)bh * NN + q0) * DD;
  const u16* KVp = KVg + (size_t)bh * (32 * 8192);

  // Q fragments straight from global (B-operand layout: row=r16, k=q*8+j)
  short8 qf[2][2];  // [nj][ks]
#pragma unroll
  for (int nj = 0; nj < 2; nj++)
#pragma unroll
    for (int ks = 0; ks < 2; ks++)
      qf[nj][ks] = *(const short8*)(Qp + (wave * 32 + nj * 16 + r16) * 64 + ks * 32 + q * 8);

  // stage K/V tile 0 into buf 0 (pure linear copy: 1024 chunks x 16B)
#pragma unroll
  for (int i = 0; i < 4; i++) {
    int c = i * 256 + tid;
    async16(KVp + c * 8, &KVd[0][c * 8]);
  }
  __syncthreads();  // tile0 landed

  f32x4 o[2][4];    // O accumulator [ri][ci]
  f32x4 ol[2];      // row-sum accumulator via ones-MFMA
#pragma unroll
  for (int i = 0; i < 2; i++) {
    ol[i] = (f32x4){0.f, 0.f, 0.f, 0.f};
#pragma unroll
    for (int j = 0; j < 4; j++) o[i][j] = (f32x4){0.f, 0.f, 0.f, 0.f};
  }
  const short8 ones = {16256, 16256, 16256, 16256, 16256, 16256, 16256, 16256};  // bf16 1.0

  for (int j = 0; j < 32; j++) {
    const int buf = j & 1;
    // prefetch tile j+1 into the other buffer (overlaps with compute below)
    if (j < 31) {
      const u16* src = KVp + (size_t)(j + 1) * 8192;
#pragma unroll
      for (int i = 0; i < 4; i++) {
        int c = i * 256 + tid;
        async16(src + c * 8, &KVd[buf ^ 1][c * 8]);
      }
    }

    // S^T = K.Q^T : st[mi][nj]; m = keys, n = q-rows (already in exp2 domain)
    f32x4 st[4][2];
#pragma unroll
    for (int mi = 0; mi < 4; mi++)
#pragma unroll
      for (int nj = 0; nj < 2; nj++) st[mi][nj] = (f32x4){0.f, 0.f, 0.f, 0.f};
#pragma unroll
    for (int ks = 0; ks < 2; ks++) {
      short8 kf[4];
#pragma unroll
      for (int mi = 0; mi < 4; mi++)
        kf[mi] = *(const short8*)&KVd[buf][ks * 2048 + mi * 512 + lane * 8];
      __builtin_amdgcn_s_setprio(1);
#pragma unroll
      for (int mi = 0; mi < 4; mi++)
#pragma unroll
        for (int nj = 0; nj < 2; nj++)
          st[mi][nj] = __builtin_amdgcn_mfma_f32_16x16x32_bf16(kf[mi], qf[nj][ks], st[mi][nj], 0, 0, 0);
      __builtin_amdgcn_s_setprio(0);
    }

    // p = exp2(s'); pack in-register (keys stay lane-local; no LDS round-trip)
    uint2 pka[4][2];  // [mi][nj] = (pk(r0,r1), pk(r2,r3))
#pragma unroll
    for (int mi = 0; mi < 4; mi++)
#pragma unroll
      for (int nj = 0; nj < 2; nj++) {
        float p0 = EXP2(st[mi][nj][0]);
        float p1 = EXP2(st[mi][nj][1]);
        float p2 = EXP2(st[mi][nj][2]);
        float p3 = EXP2(st[mi][nj][3]);
        pka[mi][nj].x = pk2(p0, p1);
        pka[mi][nj].y = pk2(p2, p3);
      }

    // O += P.V ; row-sums += P.1  (A-frags assembled in-register)
#pragma unroll
    for (int kp = 0; kp < 2; kp++) {
      short8 vf[4];
#pragma unroll
      for (int ci = 0; ci < 4; ci++)
        vf[ci] = *(const short8*)&KVd[buf][4096 + kp * 2048 + ci * 512 + lane * 8];
      __builtin_amdgcn_s_setprio(1);
#pragma unroll
      for (int ri = 0; ri < 2; ri++) {
        union { uint4 u; short8 s; } a;
        a.u.x = pka[2 * kp][ri].x;
        a.u.y = pka[2 * kp][ri].y;
        a.u.z = pka[2 * kp + 1][ri].x;
        a.u.w = pka[2 * kp + 1][ri].y;
#pragma unroll
        for (int ci = 0; ci < 4; ci++)
          o[ri][ci] = __builtin_amdgcn_mfma_f32_16x16x32_bf16(a.s, vf[ci], o[ri][ci], 0, 0, 0);
        ol[ri] = __builtin_amdgcn_mfma_f32_16x16x32_bf16(a.s, ones, ol[ri], 0, 0, 0);
      }
      __builtin_amdgcn_s_setprio(0);
    }

    __syncthreads();  // drains prefetch (issued a full compute phase ago); buffer handoff
  }

  // epilogue: O/l -> Ob[b][n][h*64+d] bf16; no reduction needed (ones-trick)
  const int b = bh >> 4, h = bh & 15;
#pragma unroll
  for (int ri = 0; ri < 2; ri++)
#pragma unroll
    for (int r = 0; r < 4; r++) {
      const float inv = 1.0f / ol[ri][r];
      const int n = q0 + wave * 32 + ri * 16 + q * 4 + r;
#pragma unroll
      for (int ci = 0; ci < 4; ci++) {
        const int d = ci * 16 + r16;
        Ob[((size_t)(b * NN + n)) * EE + h * 64 + d] = f2bf(o[ri][ci][r] * inv);
      }
    }
}

// ---------------- launch ----------------

extern "C" void kernel_launch(void* const* d_in, const int* in_sizes, int n_in,
                              void* d_out, int out_size, void* d_ws, size_t ws_size,
                              hipStream_t stream) {
  const float* x     = (const float*)d_in[0];
  const float* Wqkv  = (const float*)d_in[1];
  const float* bqkv  = (const float*)d_in[2];
  const float* Wproj = (const float*)d_in[3];
  const float* bproj = (const float*)d_in[4];
  float* out = (float*)d_out;
  char* ws = (char*)d_ws;

  u16* Xb     = (u16*)(ws);                      // 16MB (aliased by Ob after gemm_qkv)
  u16* Ob     = Xb;
  u16* Qb     = (u16*)(ws + (size_t)(16 << 20)); // 16MB (pre-scaled by CS)
  u16* KVt    = (u16*)(ws + (size_t)(32 << 20)); // 32MB merged K/V chunk layout
  u16* WqkvT  = (u16*)(ws + (size_t)(64 << 20)); // 6MB   [c'][k]
  u16* WprojT = (u16*)(ws + (size_t)(72 << 20)); // 2MB   [e_out][e_in]

  prep_kernel<<<12288, 256, 0, stream>>>(x, Xb, Wqkv, WqkvT, Wproj, WprojT);
  gemm_qkv<<<dim3(24, 64), 256, 0, stream>>>(Xb, WqkvT, bqkv, Qb, KVt);
  attn_kernel<<<dim3(16, 64), 256, 0, stream>>>(Qb, KVt, Ob);
  gemm_proj<<<dim3(8, 64), 256, 0, stream>>>(Ob, WprojT, bproj, out);
}